// Round 10
// baseline (533.671 us; speedup 1.0000x reference)
//
#include <hip/hip_runtime.h>
#include <hip/hip_bf16.h>

// DropLearner: per-edge gumbel-sigmoid gate + top-80% select + sym degree norm.
//
// Pipeline (6 dispatches):
//   1. init_kernel  : zero rowsum+hists+state, detect int32/int64 indices
//   2. gate_kernel  : quarter-wave (16 lanes) per edge, 2 edges per group ->
//                     8 edges / 8 gathers in flight per wave. gate[e]->d_out,
//                     LDS hist of top-11 bits, last block runs radix scan 0.
//                     NO global atomics in the hot loop (R1 lesson: fused
//                     rowsum atomics cost 2.4x via memory-side atomic latency).
//   3. hist1_kernel : refine bits [20:10], last block runs scan 1
//   4. hist2_kernel : refine bits [9:0],  last block runs scan 2 (exact k-th)
//   5. rowsum_kernel: exact masked atomicAdd gate into rowsum[row]
//   6. values_kernel: d_out[e] = kept ? gate * f(rs[r]) * f(rs[c]) : 0,
//                     f(rs) = rs>0 ? min(rs^-0.5,10) : 10 inline.
//
// state[]: 0=threshold bits, 1=kRem, 2=ctr_gate, 3=is64, 4=ctr_h1, 5=ctr_h2

#define BIASF 0.0001f
#define H_DIM 128

__device__ __forceinline__ int load_idx(const void* ei, long long pos, int is64) {
    if (is64) return (int)((const long long*)ei)[pos];
    return ((const int*)ei)[pos];
}

// last-block radix scan: find bin b with cnt(>b) < kRem <= cnt(>=b)
__device__ void scan_finalize(unsigned* hist, int nb, int shift,
                              unsigned kRem, unsigned pfx, unsigned* state) {
    const int C = nb / 256;            // 8 or 4
    __shared__ unsigned csum[256];
    __shared__ unsigned sfx[256];
    const int t = threadIdx.x;
    unsigned vals[8];
    unsigned s = 0;
    for (int i = 0; i < C; ++i) {
        vals[i] = atomicAdd(&hist[t * C + i], 0u);  // coherent read
        s += vals[i];
    }
    csum[t] = s;
    __syncthreads();
    if (t == 0) {
        unsigned acc = 0;
        for (int i = 255; i >= 0; --i) { sfx[i] = acc; acc += csum[i]; }
    }
    __syncthreads();
    unsigned g = sfx[t];               // count strictly above this chunk
    for (int j = C - 1; j >= 0; --j) {
        unsigned cb = vals[j];
        if (g < kRem && g + cb >= kRem) {
            state[0] = pfx | ((unsigned)(t * C + j) << shift);
            state[1] = kRem - g;
        }
        g += cb;
    }
}

// ------------------------------------------------------------------- init
__global__ __launch_bounds__(256) void init_kernel(
    unsigned* __restrict__ zbase, long long zwords,
    const unsigned* __restrict__ ei32, unsigned* __restrict__ state) {
    long long i = (long long)blockIdx.x * 256 + threadIdx.x;
    const long long stride = (long long)gridDim.x * 256;
    for (; i < zwords; i += stride) zbase[i] = 0u;
    if (blockIdx.x == 0 && threadIdx.x == 0) {
        for (int j = 0; j < 8; ++j) state[j] = 0u;
        unsigned orall = 0;
        for (int j = 0; j < 64; ++j) orall |= ei32[2 * j + 1];
        state[3] = (orall == 0u) ? 1u : 0u;   // int64 with zero hi-words
    }
}

// ------------------------------------------------------------------- gate
// 16-lane group per edge pair: lane l covers floats [l*8, l*8+8) of each row.
// 8 independent float4 gathers in flight per wave; idx prefetch for the next
// iteration issued under the current gathers; noise math after gather issue.
__global__ __launch_bounds__(256) void gate_kernel(
    const float* __restrict__ x, const void* __restrict__ ei,
    const float* __restrict__ noise, float* __restrict__ gate_out,
    unsigned* __restrict__ hist0, unsigned* __restrict__ state,
    long long E, unsigned k0) {
    __shared__ unsigned lhist[2048];
    for (int i = threadIdx.x; i < 2048; i += 256) lhist[i] = 0;
    __syncthreads();
    const int is64 = (int)state[3];
    const int g    = threadIdx.x >> 4;    // 0..15 group id in block
    const int l    = threadIdx.x & 15;    // lane in group
    const long long step = (long long)gridDim.x * 32;

    long long base = (long long)blockIdx.x * 32 + g * 2;
    int r0 = 0, c0 = 0, r1 = 0, c1 = 0;
    if (base < E) {
        r0 = load_idx(ei, base, is64);
        c0 = load_idx(ei, E + base, is64);
        const bool v1 = (base + 1 < E);
        r1 = v1 ? load_idx(ei, base + 1, is64) : r0;
        c1 = v1 ? load_idx(ei, E + base + 1, is64) : c0;
    }

    for (; base < E; ) {
        // issue the 8 gathers for the current edge pair FIRST
        const float4* pa0 = (const float4*)(x + (long long)r0 * H_DIM) + l * 2;
        const float4* pb0 = (const float4*)(x + (long long)c0 * H_DIM) + l * 2;
        const float4* pa1 = (const float4*)(x + (long long)r1 * H_DIM) + l * 2;
        const float4* pb1 = (const float4*)(x + (long long)c1 * H_DIM) + l * 2;
        float4 a00 = pa0[0], a01 = pa0[1];
        float4 b00 = pb0[0], b01 = pb0[1];
        float4 a10 = pa1[0], a11 = pa1[1];
        float4 b10 = pb1[0], b11 = pb1[1];

        // prefetch next iteration's indices under the gathers
        const long long nbase = base + step;
        int nr0 = 0, nc0 = 0, nr1 = 0, nc1 = 0;
        if (nbase < E) {
            nr0 = load_idx(ei, nbase, is64);
            nc0 = load_idx(ei, E + nbase, is64);
            const bool nv1 = (nbase + 1 < E);
            nr1 = nv1 ? load_idx(ei, nbase + 1, is64) : nr0;
            nc1 = nv1 ? load_idx(ei, E + nbase + 1, is64) : nc0;
        }

        // noise-side math under the gathers (lanes 0,1 of each group)
        float ratio2 = 0.0f;
        if (l < 2) {
            const long long e = base + l;
            float nz  = (e < E) ? noise[e] : 0.5f;
            float eps = 0.9999f - 0.9998f * nz;   // (BIAS-(1-BIAS))*nz+(1-BIAS)
            float ratio = (1.0f - eps) / eps;     // e^{-lnz}... = (1-eps)/eps
            ratio2 = ratio * ratio;               // e^{-2*logit_noise}
        }

        // dot-product partials (waits on gathers here)
        float p0 = a00.x*b00.x + a00.y*b00.y + a00.z*b00.z + a00.w*b00.w
                 + a01.x*b01.x + a01.y*b01.y + a01.z*b01.z + a01.w*b01.w;
        float p1 = a10.x*b10.x + a10.y*b10.y + a10.z*b10.z + a10.w*b10.w
                 + a11.x*b11.x + a11.y*b11.y + a11.z*b11.z + a11.w*b11.w;
        #pragma unroll
        for (int off = 8; off; off >>= 1) {
            p0 += __shfl_xor(p0, off);
            p1 += __shfl_xor(p1, off);
        }

        if (l < 2 && base + l < E) {
            const float p = (l == 0) ? p0 : p1;
            // gate = sigmoid((logit_noise + p)/0.5) = 1/(1 + ratio2*e^{-2p})
            float t = ratio2 * expf(-2.0f * p);
            float gate = 1.0f / (1.0f + t);
            gate_out[base + l] = gate;
            atomicAdd(&lhist[__float_as_uint(gate) >> 21], 1u);
        }

        base = nbase;
        r0 = nr0; c0 = nc0; r1 = nr1; c1 = nc1;
    }

    __syncthreads();
    for (int i = threadIdx.x; i < 2048; i += 256) {
        unsigned v = lhist[i];
        if (v) atomicAdd(&hist0[i], v);
    }
    __threadfence();
    __shared__ unsigned isLast;
    if (threadIdx.x == 0)
        isLast = (atomicAdd(&state[2], 1u) == (unsigned)gridDim.x - 1u);
    __syncthreads();
    if (isLast) scan_finalize(hist0, 2048, 21, k0, 0u, state);
}

// ----------------------------------------------------- refine histograms
template <int LEVEL>
__global__ __launch_bounds__(256) void hist_kernel(
    const float* __restrict__ gate, unsigned* __restrict__ hist,
    unsigned* __restrict__ state, long long E4, long long E) {
    __shared__ unsigned lh[2048];
    const int nb = (LEVEL == 1) ? 2048 : 1024;
    for (int i = threadIdx.x; i < nb; i += 256) lh[i] = 0;
    __syncthreads();
    const unsigned pfx  = state[0];
    const unsigned kRem = state[1];
    const long long stride = (long long)gridDim.x * 256;
    for (long long q = (long long)blockIdx.x * 256 + threadIdx.x; q < E4;
         q += stride) {
        float4 g4 = ((const float4*)gate)[q];
        float gv[4] = {g4.x, g4.y, g4.z, g4.w};
        #pragma unroll
        for (int j = 0; j < 4; ++j) {
            unsigned key = __float_as_uint(gv[j]);
            if (LEVEL == 1) {
                if ((key >> 21) == (pfx >> 21))
                    atomicAdd(&lh[(key >> 10) & 2047], 1u);
            } else {
                if ((key >> 10) == (pfx >> 10))
                    atomicAdd(&lh[key & 1023], 1u);
            }
        }
    }
    if (blockIdx.x == 0) {  // scalar tail (E not multiple of 4)
        for (long long e = E4 * 4 + threadIdx.x; e < E; e += 256) {
            unsigned key = __float_as_uint(gate[e]);
            if (LEVEL == 1) {
                if ((key >> 21) == (pfx >> 21))
                    atomicAdd(&lh[(key >> 10) & 2047], 1u);
            } else {
                if ((key >> 10) == (pfx >> 10))
                    atomicAdd(&lh[key & 1023], 1u);
            }
        }
    }
    __syncthreads();
    for (int i = threadIdx.x; i < nb; i += 256) {
        unsigned v = lh[i];
        if (v) atomicAdd(&hist[i], v);
    }
    __threadfence();
    __shared__ unsigned isLast;
    if (threadIdx.x == 0)
        isLast = (atomicAdd(&state[LEVEL == 1 ? 4 : 5], 1u) ==
                  (unsigned)gridDim.x - 1u);
    __syncthreads();
    if (isLast)
        scan_finalize(hist, nb, (LEVEL == 1) ? 10 : 0, kRem, pfx, state);
}

// ---------------------------------------------------------------- rowsum
// exact: only kept edges contribute (threshold known by now)
__global__ __launch_bounds__(256) void rowsum_kernel(
    const float* __restrict__ gate, const void* __restrict__ ei,
    const unsigned* __restrict__ state, float* __restrict__ rowsum,
    long long E) {
    const unsigned tbits = state[0];
    const int is64 = (int)state[3];
    const long long stride = (long long)gridDim.x * 256;
    for (long long e = (long long)blockIdx.x * 256 + threadIdx.x; e < E;
         e += stride) {
        float gv = gate[e];
        if (__float_as_uint(gv) >= tbits) {
            int r = load_idx(ei, e, is64);
            atomicAdd(&rowsum[r], gv);
        }
    }
}

// ----------------------------------------------------------------- values
__device__ __forceinline__ float dinv_of(float rs) {
    return (rs > 0.0f) ? fminf(1.0f / sqrtf(rs), 10.0f) : 10.0f;
}

__global__ __launch_bounds__(256) void values_kernel(
    float* __restrict__ gate_io, const void* __restrict__ ei,
    const unsigned* __restrict__ state, const float* __restrict__ rowsum,
    long long E) {
    const unsigned tbits = state[0];
    const int is64 = (int)state[3];
    const long long stride = (long long)gridDim.x * 256;
    for (long long e = (long long)blockIdx.x * 256 + threadIdx.x; e < E;
         e += stride) {
        float gv = gate_io[e];
        float v  = 0.0f;
        if (__float_as_uint(gv) >= tbits) {
            int r = load_idx(ei, e, is64);
            int c = load_idx(ei, E + e, is64);
            v = gv * dinv_of(rowsum[r]) * dinv_of(rowsum[c]);
        }
        gate_io[e] = v;
    }
}

extern "C" void kernel_launch(void* const* d_in, const int* in_sizes, int n_in,
                              void* d_out, int out_size, void* d_ws, size_t ws_size,
                              hipStream_t stream) {
    const float* x     = (const float*)d_in[0];
    const void*  ei    = d_in[1];
    const float* noise = (const float*)d_in[2];
    float* out = (float*)d_out;

    const long long N  = (long long)in_sizes[0] / H_DIM;
    const long long E  = (long long)in_sizes[1] / 2;
    const long long E4 = E / 4;
    const unsigned  k  = (unsigned)((double)E * 0.8);  // KEEP_FRAC

    // workspace: rowsum[N] hist0[2048] hist1[2048] hist2[1024] | state[8]
    float*    rowsum = (float*)d_ws;
    unsigned* hist0  = (unsigned*)(rowsum + N);
    unsigned* hist1  = hist0 + 2048;
    unsigned* hist2  = hist1 + 2048;
    unsigned* state  = hist2 + 1024;
    (void)ws_size; (void)n_in; (void)out_size;

    const long long zwords = N + 2048 + 2048 + 1024;
    int iblocks = (int)((zwords + 255) / 256);
    init_kernel<<<iblocks, 256, 0, stream>>>((unsigned*)d_ws, zwords,
                                             (const unsigned*)ei, state);

    long long gwant = (E + 31) / 32;
    int gblocks = (int)((gwant < 2048) ? gwant : 2048);
    gate_kernel<<<gblocks, 256, 0, stream>>>(x, ei, noise, out, hist0,
                                             state, E, k);

    long long hwant = (E4 + 255) / 256;
    int hblocks = (int)((hwant < 2048) ? hwant : 2048);
    hist_kernel<1><<<hblocks, 256, 0, stream>>>(out, hist1, state, E4, E);
    hist_kernel<2><<<hblocks, 256, 0, stream>>>(out, hist2, state, E4, E);

    long long ewant = (E + 255) / 256;
    int eblocks = (int)((ewant < 2048) ? ewant : 2048);
    rowsum_kernel<<<eblocks, 256, 0, stream>>>(out, ei, state, rowsum, E);
    values_kernel<<<eblocks, 256, 0, stream>>>(out, ei, state, rowsum, E);
}